// Round 8
// baseline (337.395 us; speedup 1.0000x reference)
//
#include <hip/hip_runtime.h>
#include <math.h>

// Problem constants
#define E_TOT 1048576
#define NB    64          // graphs
#define HD    128         // hidden dim
#define NN1   65536       // nodes stage1 (64*1024)
#define NN2   32768       // nodes stage2 (64*512)
#define NN3   16384       // nodes stage3 (64*256)
#define CAP   18432       // per-graph edge bin capacity (mean 16384 + 16 sigma)
#define WST   140         // swizzled sW row stride (max pos 136 + 4)
#define PSTR  64          // padded CSR stride (ints/node); deg max ~45 (Poisson 16)
#define SMEM_PREP (2*16*128*4 + 2*16*WST*4)   // 34304B: gemm dbuf tiles

// ----------------------------------------------------------------------------
// edge_index dtype probe + gcur clear + csr2 tail pad clear (safe unguarded
// 8-wide edge-record loads in agg_lds_kernel).
__global__ void probe_kernel(const int* __restrict__ ei, int* __restrict__ flag,
                             int* __restrict__ gcur, int2* __restrict__ csr2) {
    int t = threadIdx.x;
    if (t < 64) { gcur[t] = 0; csr2[E_TOT + t] = make_int2(0, 0); }
    if (blockIdx.x == 0 && t == 0) {
        int w = 1;
        for (int i = 1; i < 64; i += 2) if (ei[i] != 0) { w = 0; break; }
        *flag = w;
    }
}

// ----------------------------------------------------------------------------
// Stage-1 edge build, phase 1: standalone 256-thr block-level counting sort by
// graph id (un-merged from the GEMM: both bodies are DS-pipe-heavy and
// serialized at the shared CU LDS port when co-resident). Per-thread work is
// identical to all previous rounds -> identical edge ordering.
__global__ __launch_bounds__(256) void bin_pack_kernel(const int* __restrict__ ei,
                                                       const int* __restrict__ wflag,
                                                       int* __restrict__ bins,
                                                       int* __restrict__ gcur) {
    __shared__ int hist[64];
    __shared__ int base[64];
    __shared__ int gpos[64];
    __shared__ int stage[4096];
    const int t = threadIdx.x;
    const int wide = *wflag;
    const int e0 = blockIdx.x * 4096;
    const int2* ei2 = (const int2*)ei;

    int pk[16];
    #pragma unroll
    for (int j = 0; j < 16; ++j) {
        int e = e0 + j * 256 + t;
        int s, d;
        if (wide) { s = ei2[e].x; d = ei2[E_TOT + e].x; }
        else      { s = ei[e];    d = ei[E_TOT + e]; }
        int g = d >> 10;
        pk[j] = (g << 20) | ((d & 1023) << 10) | (s & 1023);
    }
    if (t < 64) hist[t] = 0;
    __syncthreads();
    #pragma unroll
    for (int j = 0; j < 16; ++j) atomicAdd(&hist[pk[j] >> 20], 1);
    __syncthreads();
    if (t < 64) {
        int v = hist[t];
        int inc = v;
        #pragma unroll
        for (int d = 1; d < 64; d <<= 1) { int u = __shfl_up(inc, d); if (t >= d) inc += u; }
        base[t] = inc - v;                       // exclusive within tile
        gpos[t] = atomicAdd(&gcur[t], v);        // reserve global run
    }
    __syncthreads();
    if (t < 64) hist[t] = base[t];               // reuse as cursor
    __syncthreads();
    #pragma unroll
    for (int j = 0; j < 16; ++j) {
        int p = atomicAdd(&hist[pk[j] >> 20], 1);
        stage[p] = pk[j];
    }
    __syncthreads();
    #pragma unroll
    for (int j = 0; j < 16; ++j) {
        int i = j * 256 + t;
        int v = stage[i];
        int g = v >> 20;
        int dst = gpos[g] + (i - base[g]);
        if (dst < CAP) bins[g * CAP + dst] = v;
    }
}

// ----------------------------------------------------------------------------
// Tiled f32 GEMM body, 512 threads (dynamic-LDS): Y[bid*128..+128) = X' @ W,
// X' row r = sel ? X[sel[r]]*scal[r] : X[r]. 128x128 tile, BK=16 dbuf,
// swizzled sW; acc[4][8]/thread (8 waves/block). Bit-exact: each output
// element's k-accumulation order (k ascending, fmaf chain, staged x*sc
// multiply) is unchanged; only element->thread mapping moved.
// FUSED READOUT (part != nullptr): the staged sXT tile IS X' = h[sel]*scal.
// After each phase's sync, threads t < 2048/CH reduce feature (k0+kk) over
// chunk ch's CH rows serially in node order (bit-identical part values).
__device__ __forceinline__ void gemm_body(char* smem, const float* __restrict__ X,
                                          const int* __restrict__ sel,
                                          const float* __restrict__ scal,
                                          const float* __restrict__ W,
                                          float* __restrict__ Y, int bid,
                                          float* __restrict__ part, int CH) {
    float* sXT = (float*)smem;                 // [2][16][128] (k-major)
    float* sW  = sXT + 2 * 16 * 128;           // [2][16][WST]
    const int t = threadIdx.x;                 // 0..511
    const long long row0 = (long long)bid * 128;
    const int r0 = (t >> 4) << 2;              // 32 row groups x 4 rows
    const int c0 = (t & 15) << 3;              // 16 col groups x 8 cols
    const int wofs = c0 + ((c0 >> 5) << 2);
    const int lm  = t >> 2;                    // X-stage: row 0..127
    const int lk  = (t & 3) << 2;              // X-stage: k sub-offset 0/4/8/12
    const int wk  = t >> 5;                    // W-stage: k row 0..15
    const int wc4 = (t & 31) << 2;             // W-stage: col 0..124 (4-aligned)
    const int wpos = wc4 + ((wc4 >> 5) << 2);  // same col->pos map as reads

    const float* xrow;
    float sc;
    if (sel) { xrow = X + (long long)sel[row0 + lm] * 128; sc = scal[row0 + lm]; }
    else     { xrow = X + (row0 + lm) * 128;               sc = 1.f; }

    float acc[4][8];
    #pragma unroll
    for (int i = 0; i < 4; ++i)
        #pragma unroll
        for (int j = 0; j < 8; ++j) acc[i][j] = 0.f;

    {
        float4 xa = *(const float4*)(xrow + lk);
        float4 wa = *(const float4*)(W + wk * 128 + wc4);
        sXT[(lk + 0) * 128 + lm] = xa.x * sc; sXT[(lk + 1) * 128 + lm] = xa.y * sc;
        sXT[(lk + 2) * 128 + lm] = xa.z * sc; sXT[(lk + 3) * 128 + lm] = xa.w * sc;
        *(float4*)&sW[wk * WST + wpos] = wa;
    }
    int cur = 0;
    for (int k0 = 0; k0 < 128; k0 += 16) {
        __syncthreads();
        // fused readout: reduce current tile's 16 feature columns per chunk
        if (part) {
            int nu = 2048 / CH;                // 16 features x (128/CH) chunks
            if (t < nu) {
                int kk = t & 15, ch = t >> 4;
                const float* col = &sXT[(cur * 16 + kk) * 128 + ch * CH];
                float m = -INFINITY, s = 0.f;
                for (int n = 0; n < CH; ++n) {
                    float v = col[n];
                    m = fmaxf(m, v);
                    s += v;
                }
                size_t gc = (size_t)bid * (128 / CH) + ch;
                part[gc * 256 + k0 + kk]       = m;
                part[gc * 256 + 128 + k0 + kk] = s;
            }
        }
        const bool hasNext = (k0 + 16) < 128;
        float4 nxa, nwa;
        if (hasNext) {
            nxa = *(const float4*)(xrow + k0 + 16 + lk);
            nwa = *(const float4*)(W + (k0 + 16 + wk) * 128 + wc4);
        }
        #pragma unroll
        for (int kk = 0; kk < 16; ++kk) {
            float4 xa = *(const float4*)&sXT[(cur * 16 + kk) * 128 + r0];
            float4 wa = *(const float4*)&sW[(cur * 16 + kk) * WST + wofs];
            float4 wb = *(const float4*)&sW[(cur * 16 + kk) * WST + wofs + 4];
            float xr[4]  = {xa.x, xa.y, xa.z, xa.w};
            float wcv[8] = {wa.x, wa.y, wa.z, wa.w, wb.x, wb.y, wb.z, wb.w};
            #pragma unroll
            for (int i = 0; i < 4; ++i)
                #pragma unroll
                for (int j = 0; j < 8; ++j)
                    acc[i][j] = fmaf(xr[i], wcv[j], acc[i][j]);
        }
        if (hasNext) {
            int nxt = cur ^ 1;
            sXT[(nxt * 16 + lk + 0) * 128 + lm] = nxa.x * sc;
            sXT[(nxt * 16 + lk + 1) * 128 + lm] = nxa.y * sc;
            sXT[(nxt * 16 + lk + 2) * 128 + lm] = nxa.z * sc;
            sXT[(nxt * 16 + lk + 3) * 128 + lm] = nxa.w * sc;
            *(float4*)&sW[(nxt * 16 + wk) * WST + wpos] = nwa;
            cur = nxt;
        }
    }

    #pragma unroll
    for (int i = 0; i < 4; ++i) {
        float* yp = Y + (row0 + r0 + i) * 128 + c0;
        float4 o0; o0.x = acc[i][0]; o0.y = acc[i][1]; o0.z = acc[i][2]; o0.w = acc[i][3];
        float4 o1; o1.x = acc[i][4]; o1.y = acc[i][5]; o1.z = acc[i][6]; o1.w = acc[i][7];
        *(float4*)yp       = o0;
        *(float4*)(yp + 4) = o1;
    }
}

// ----------------------------------------------------------------------------
// Gather-GEMM + optional fused readout (all 3 stages; sel=nullptr -> plain).
__global__ __launch_bounds__(512) void gemm_fused_kernel(const float* __restrict__ Bf,
                                                         const int* __restrict__ sel,
                                                         const float* __restrict__ scal,
                                                         const float* __restrict__ W,
                                                         float* __restrict__ A,
                                                         float* __restrict__ part,
                                                         int CH) {
    extern __shared__ __align__(16) char smem[];
    gemm_body(smem, Bf, sel, scal, W, A, blockIdx.x, part, CH);
}

// ----------------------------------------------------------------------------
// Standalone pooled-CSR build -> PADDED layout (zero LDS -> full occupancy for
// the latency-bound map gathers). Survivor order = old order filtered ->
// bit-identical agg. old_stride 2 for int2 stage-1 csr.
__global__ __launch_bounds__(256) void csr_build_kernel(const int2* __restrict__ old_off2,
                                                        const int* __restrict__ old_deg,
                                                        const int* __restrict__ old_csr,
                                                        int old_stride,
                                                        const int* __restrict__ map,
                                                        const int* __restrict__ sel,
                                                        int* __restrict__ new_csr,
                                                        int* __restrict__ deg,
                                                        float* __restrict__ rs, int nnew) {
    int wid  = (blockIdx.x * blockDim.x + threadIdx.x) >> 6;
    int lane = threadIdx.x & 63;
    if (wid >= nnew) return;
    int old = sel[wid];
    int beg, end;
    if (old_off2) { int2 oe = old_off2[old]; beg = oe.x; end = oe.y; }
    else          { beg = old * PSTR; end = beg + old_deg[old]; }
    int out = wid * PSTR;
    int total = 0;
    for (int base = beg; base < end; base += 64) {
        int i = base + lane;
        int ns = -1;
        if (i < end) ns = map[old_csr[i * old_stride]];
        unsigned long long b = __ballot(ns >= 0);
        int pos = __popcll(b & ((1ULL << lane) - 1));
        if (ns >= 0 && total + pos < PSTR) new_csr[out + total + pos] = ns;
        total += __popcll(b);
    }
    if (total > PSTR) total = PSTR;
    if (lane == 0) {
        deg[wid] = total;
        rs[wid]  = rsqrtf((float)(total + 1));
    }
}

// ----------------------------------------------------------------------------
// Stage-1 edge build, phase 2: one block per graph -> int2 off2 + rs +
// norm-fused csr2 ({global src, rs[s]*rs[d]}) + degree-sorted perm (counting
// sort, ascending; used by agg_lds for divergence-free node grouping).
__global__ __launch_bounds__(1024) void graph_csr_kernel(const int* __restrict__ bins,
                                                         const int* __restrict__ gcur,
                                                         int2* __restrict__ off2,
                                                         float* __restrict__ rs,
                                                         int2* __restrict__ csr2,
                                                         int* __restrict__ perm) {
    __shared__ int   deg[1024];
    __shared__ int   cur[1024];
    __shared__ float rsl[1024];
    __shared__ int   wsum[16];
    __shared__ int   dh[64];
    __shared__ int   dc[64];
    __shared__ int   ebase_s;
    const int g = blockIdx.x, t = threadIdx.x;
    const int lane = t & 63, wv = t >> 6;

    if (t < 64) {
        int v = gcur[t];
        int inc = v;
        #pragma unroll
        for (int d = 1; d < 64; d <<= 1) { int u = __shfl_up(inc, d); if (t >= d) inc += u; }
        if (t == g) ebase_s = inc - v;
    }
    deg[t] = 0;
    if (t < 64) dh[t] = 0;
    __syncthreads();
    const int cnt = gcur[g];
    const int ebase = ebase_s;
    const int* bin = bins + g * CAP;

    for (int i = t; i < cnt; i += 1024)
        atomicAdd(&deg[(bin[i] >> 10) & 1023], 1);
    __syncthreads();

    int dv = deg[t];
    int dcap = dv < 63 ? dv : 63;
    atomicAdd(&dh[dcap], 1);                     // degree histogram
    int inc = dv;
    #pragma unroll
    for (int d = 1; d < 64; d <<= 1) { int u = __shfl_up(inc, d); if (lane >= d) inc += u; }
    if (lane == 63) wsum[wv] = inc;
    __syncthreads();
    if (t < 16) {
        int v = wsum[t];
        int inc2 = v;
        #pragma unroll
        for (int d = 1; d < 16; d <<= 1) { int u = __shfl_up(inc2, d); if (t >= d) inc2 += u; }
        wsum[t] = inc2 - v;
    }
    if (t >= 64 && t < 128) {                    // wave 1: degree-hist prefix sum
        int l2 = t - 64;
        int v2 = dh[l2];
        int inc3 = v2;
        #pragma unroll
        for (int d = 1; d < 64; d <<= 1) { int u = __shfl_up(inc3, d); if (l2 >= d) inc3 += u; }
        dc[l2] = inc3 - v2;                      // exclusive base cursor
    }
    __syncthreads();
    int ex = inc - dv + wsum[wv];
    int beg = ebase + ex;
    off2[g * 1024 + t] = make_int2(beg, beg + dv);
    float rv = rsqrtf((float)(dv + 1));
    rs[g * 1024 + t] = rv;
    rsl[t] = rv;
    cur[t] = ex;
    int r2 = atomicAdd(&dc[dcap], 1);            // rank in ascending-degree order
    perm[g * 1024 + r2] = t;
    __syncthreads();

    for (int i = t; i < cnt; i += 1024) {
        int v = bin[i];
        int s = v & 1023;
        int d = (v >> 10) & 1023;
        int p = atomicAdd(&cur[d], 1);
        csr2[ebase + p] = make_int2((g << 10) + s, __float_as_int(rsl[s] * rsl[d]));
    }
}

// ----------------------------------------------------------------------------
// Stage-1 GCN aggregation, LDS-staged per (graph, 32-feature chunk).
// grid = fc*64 + g; block = 1024 thr; LDS = 1024 x 36 floats (144KB).
// Degree-sorted node assignment (perm); direct same-address edge loads
// (VMEM broadcast). Bit-exact order throughout.
__global__ __launch_bounds__(1024) void agg_lds_kernel(const float* __restrict__ h,
                                                       const int2* __restrict__ csr2,
                                                       const int2* __restrict__ off2,
                                                       const float* __restrict__ rs,
                                                       const int* __restrict__ perm,
                                                       const float* __restrict__ bias,
                                                       const float* __restrict__ ws,
                                                       float* __restrict__ hrelu,
                                                       float* __restrict__ P) {
    __shared__ float sh[1024 * 36];
    const int t  = threadIdx.x;
    const int g  = blockIdx.x & 63;
    const int fc = blockIdx.x >> 6;
    const int nbase = g << 10;
    const float* hg = h + (size_t)nbase * 128 + fc * 32;

    // stage: 1024 rows x 32 floats; 8 consecutive lanes read 128B of one row
    #pragma unroll
    for (int it = 0; it < 8; ++it) {
        int i = it * 1024 + t;
        int r = i >> 3, p = i & 7;
        float4 v4 = *(const float4*)(hg + (size_t)r * 128 + p * 4);
        *(float4*)&sh[r * 36 + p * 4] = v4;
    }
    __syncthreads();

    const int q   = t & 7;         // feature sub-chunk lane (features qb..qb+3)
    const int grp = t >> 3;        // node group 0..127 (8 lanes each)
    const int qb  = q << 2;

    float4 bb = *(const float4*)(bias + fc * 32 + qb);
    float4 ww = *(const float4*)(ws   + fc * 32 + qb);

    for (int pass = 0; pass < 8; ++pass) {
        int lv = perm[nbase + pass * 128 + grp];   // sorted rank -> actual node
        int v  = nbase + lv;
        int2 oe = off2[v];
        int beg = oe.x, end = oe.y;
        float rv = rs[v];
        float a0 = 0.f, a1 = 0.f, a2 = 0.f, a3 = 0.f;

        int eb = beg;
        for (; eb + 8 <= end; eb += 8) {           // full batches, no guard
            #pragma unroll
            for (int j = 0; j < 8; ++j) {
                int2 e = csr2[eb + j];             // same addr across group -> bcast
                float nj = __int_as_float(e.y);
                const float4 hv4 = *(const float4*)&sh[(e.x & 1023) * 36 + qb];
                a0 = fmaf(hv4.x, nj, a0); a1 = fmaf(hv4.y, nj, a1);
                a2 = fmaf(hv4.z, nj, a2); a3 = fmaf(hv4.w, nj, a3);
            }
        }
        if (eb < end) {                            // tail batch, norm=0 padding
            #pragma unroll
            for (int j = 0; j < 8; ++j) {
                int2 e = csr2[eb + j];             // pad-safe (64-entry zero tail)
                float nj = (eb + j < end) ? __int_as_float(e.y) : 0.f;
                const float4 hv4 = *(const float4*)&sh[(e.x & 1023) * 36 + qb];
                a0 = fmaf(hv4.x, nj, a0); a1 = fmaf(hv4.y, nj, a1);
                a2 = fmaf(hv4.z, nj, a2); a3 = fmaf(hv4.w, nj, a3);
            }
        }

        float4 hv = *(const float4*)&sh[lv * 36 + qb];
        float inv = rv * rv;
        float o0 = a0 + hv.x * inv + bb.x;
        float o1 = a1 + hv.y * inv + bb.y;
        float o2 = a2 + hv.z * inv + bb.z;
        float o3 = a3 + hv.w * inv + bb.w;

        // butterfly leaf partials for lane li = fc*8+q (exact old values)
        float pa = o0 * ww.x + o1 * ww.y;
        float pb = o2 * ww.z + o3 * ww.w;
        *(float2*)(P + (size_t)v * 64 + (fc * 8 + q) * 2) = make_float2(pa, pb);

        float4 o;
        o.x = fmaxf(o0, 0.f); o.y = fmaxf(o1, 0.f);
        o.z = fmaxf(o2, 0.f); o.w = fmaxf(o3, 0.f);
        *(float4*)(hrelu + (size_t)v * 128 + fc * 32 + qb) = o;
    }
}

// ----------------------------------------------------------------------------
// Stage-1 score finalize: combine per-lane butterfly partials into score[v].
// Exact 31-add tree per array, same operand order as the old __shfl_xor
// butterfly at lane 0 (bit-identical).
__global__ __launch_bounds__(256) void score1_kernel(const float* __restrict__ P,
                                                     float* __restrict__ score) {
    int v = blockIdx.x * 256 + threadIdx.x;
    const float* buf = P + (size_t)v * 64;
    float a[32], b[32];
    #pragma unroll
    for (int i2 = 0; i2 < 16; ++i2) {
        float4 v4 = *(const float4*)(buf + i2 * 4);
        a[i2 * 2]     = v4.x; b[i2 * 2]     = v4.y;
        a[i2 * 2 + 1] = v4.z; b[i2 * 2 + 1] = v4.w;
    }
    float ua[16], ub[16];
    #pragma unroll
    for (int l = 0; l < 16; ++l) { ua[l] = a[l] + a[l + 16]; ub[l] = b[l] + b[l + 16]; }
    float va[8], vb[8];
    #pragma unroll
    for (int l = 0; l < 8; ++l) { va[l] = ua[l] + ua[l + 8]; vb[l] = ub[l] + ub[l + 8]; }
    float wa[4], wb[4];
    #pragma unroll
    for (int l = 0; l < 4; ++l) { wa[l] = va[l] + va[l + 4]; wb[l] = vb[l] + vb[l + 4]; }
    float xa0 = wa[0] + wa[2], xa1 = wa[1] + wa[3];
    float xb0 = wb[0] + wb[2], xb1 = wb[1] + wb[3];
    score[v] = (xa0 + xa1) + (xb0 + xb1);
}

// ----------------------------------------------------------------------------
// GCN aggregation, dual-node waves (stages 2/3, padded CSR + rs gather).
__global__ __launch_bounds__(256) void agg_kernel(const float* __restrict__ h,
                                                  const int* __restrict__ csr,
                                                  const int2* __restrict__ off2,
                                                  const int* __restrict__ degp,
                                                  const float* __restrict__ rs,
                                                  const float* __restrict__ bias,
                                                  const float* __restrict__ ws,
                                                  float* __restrict__ hrelu,
                                                  float* __restrict__ score,
                                                  int npg, int lbshift, int padded) {
    const int lane = threadIdx.x & 63;
    const int wvb  = threadIdx.x >> 6;      // wave in block: 0..3
    const int half = lane >> 5;             // 0/1: which node of the wave
    const int li   = lane & 31;
    int b   = blockIdx.x;
    int xcd = b & 7;
    int i   = b >> 3;
    int gi  = i >> lbshift;
    int lb  = i & ((1 << lbshift) - 1);
    int g   = xcd + (gi << 3);
    int v   = g * npg + (lb << 3) + (wvb << 1) + half;   // 8 nodes/block, 2/wave

    int beg, end;
    if (padded) { beg = v * PSTR; end = beg + degp[v]; }
    else        { int2 oe = off2[v]; beg = oe.x; end = oe.y; }
    float rv = rs[v];
    const float4* h4 = (const float4*)h;
    float ax = 0.f, ay = 0.f, az = 0.f, aw = 0.f;

    for (int base = beg; base < end; base += 32) {
        int idx = base + li;
        int sv = (idx < end) ? csr[idx] : 0;
        int m = end - base; if (m > 32) m = 32;
        int j = 0;
        for (; j + 8 <= m; j += 8) {
            int s0 = __shfl(sv, j,     32);
            int s1 = __shfl(sv, j + 1, 32);
            int s2 = __shfl(sv, j + 2, 32);
            int s3 = __shfl(sv, j + 3, 32);
            int s4 = __shfl(sv, j + 4, 32);
            int s5 = __shfl(sv, j + 5, 32);
            int s6 = __shfl(sv, j + 6, 32);
            int s7 = __shfl(sv, j + 7, 32);
            float n0 = rs[s0] * rv, n1 = rs[s1] * rv, n2 = rs[s2] * rv, n3 = rs[s3] * rv;
            float n4 = rs[s4] * rv, n5 = rs[s5] * rv, n6 = rs[s6] * rv, n7 = rs[s7] * rv;
            float4 v0 = h4[(long long)s0 * 32 + li];
            float4 v1 = h4[(long long)s1 * 32 + li];
            float4 v2 = h4[(long long)s2 * 32 + li];
            float4 v3 = h4[(long long)s3 * 32 + li];
            float4 v4 = h4[(long long)s4 * 32 + li];
            float4 v5 = h4[(long long)s5 * 32 + li];
            float4 v6 = h4[(long long)s6 * 32 + li];
            float4 v7 = h4[(long long)s7 * 32 + li];
            ax = fmaf(v0.x, n0, ax); ay = fmaf(v0.y, n0, ay); az = fmaf(v0.z, n0, az); aw = fmaf(v0.w, n0, aw);
            ax = fmaf(v1.x, n1, ax); ay = fmaf(v1.y, n1, ay); az = fmaf(v1.z, n1, az); aw = fmaf(v1.w, n1, aw);
            ax = fmaf(v2.x, n2, ax); ay = fmaf(v2.y, n2, ay); az = fmaf(v2.z, n2, az); aw = fmaf(v2.w, n2, aw);
            ax = fmaf(v3.x, n3, ax); ay = fmaf(v3.y, n3, ay); az = fmaf(v3.z, n3, az); aw = fmaf(v3.w, n3, aw);
            ax = fmaf(v4.x, n4, ax); ay = fmaf(v4.y, n4, ay); az = fmaf(v4.z, n4, az); aw = fmaf(v4.w, n4, aw);
            ax = fmaf(v5.x, n5, ax); ay = fmaf(v5.y, n5, ay); az = fmaf(v5.z, n5, az); aw = fmaf(v5.w, n5, aw);
            ax = fmaf(v6.x, n6, ax); ay = fmaf(v6.y, n6, ay); az = fmaf(v6.z, n6, az); aw = fmaf(v6.w, n6, aw);
            ax = fmaf(v7.x, n7, ax); ay = fmaf(v7.y, n7, ay); az = fmaf(v7.z, n7, az); aw = fmaf(v7.w, n7, aw);
        }
        for (; j < m; ++j) {
            int s = __shfl(sv, j, 32);
            float n = rs[s] * rv;
            float4 vv = h4[(long long)s * 32 + li];
            ax = fmaf(vv.x, n, ax); ay = fmaf(vv.y, n, ay);
            az = fmaf(vv.z, n, az); aw = fmaf(vv.w, n, aw);
        }
    }

    float4 hv = h4[(long long)v * 32 + li];
    float inv = rv * rv;
    float4 bb = ((const float4*)bias)[li];
    float4 ww = ((const float4*)ws)[li];
    float o0 = ax + hv.x * inv + bb.x;
    float o1 = ay + hv.y * inv + bb.y;
    float o2 = az + hv.z * inv + bb.z;
    float o3 = aw + hv.w * inv + bb.w;

    // bit-exact emulation of the old 64-lane score butterfly
    float pa = o0 * ww.x + o1 * ww.y;   // old lane 2*li partial
    float pb = o2 * ww.z + o3 * ww.w;   // old lane 2*li+1 partial
    #pragma unroll
    for (int dd = 16; dd; dd >>= 1) {
        pa += __shfl_xor(pa, dd, 32);
        pb += __shfl_xor(pb, dd, 32);
    }
    float p = pa + pb;                  // old d=1 step, lane-0 (even) order
    if (li == 0) score[v] = p;

    float4 o;
    o.x = fmaxf(o0, 0.f); o.y = fmaxf(o1, 0.f);
    o.z = fmaxf(o2, 0.f); o.w = fmaxf(o3, 0.f);
    ((float4*)hrelu)[(long long)v * 32 + li] = o;
}

// ----------------------------------------------------------------------------
// per-graph top-k via bitonic sort (descending). Launch with n threads (n<=1024).
__global__ __launch_bounds__(1024) void topk_kernel(const float* __restrict__ score,
                                                    int* __restrict__ newpos,
                                                    int* __restrict__ sel,
                                                    float* __restrict__ scale,
                                                    int n, int k) {
    __shared__ float key[1024];
    __shared__ int   kid[1024];
    int g = blockIdx.x, t = threadIdx.x;
    key[t] = score[g * n + t];
    kid[t] = t;
    __syncthreads();
    for (int kk = 2; kk <= n; kk <<= 1) {
        for (int j = kk >> 1; j > 0; j >>= 1) {
            int ixj = t ^ j;
            if (ixj > t) {
                bool dir = ((t & kk) == 0);
                float a = key[t], b = key[ixj];
                if ((a < b) == dir) {
                    key[t] = b; key[ixj] = a;
                    int tmp = kid[t]; kid[t] = kid[ixj]; kid[ixj] = tmp;
                }
            }
            __syncthreads();
        }
    }
    int old = g * n + kid[t];
    if (t < k) {
        int nid = g * k + t;
        newpos[old] = nid;
        sel[nid]    = old;
        scale[nid]  = tanhf(key[t]);
    } else {
        newpos[old] = -1;
    }
}

// ----------------------------------------------------------------------------
// two-phase readout, pass A (plain, for stage-3 hrelu).
__global__ __launch_bounds__(128) void readout_part_kernel(const float* __restrict__ h,
                                                           float* __restrict__ part, int npg) {
    int b = blockIdx.x;
    int g = b >> 3, c = b & 7;
    int f = threadIdx.x;
    int chunk = npg >> 3;
    const float* base = h + ((long long)g * npg + (long long)c * chunk) * 128;
    float m = -INFINITY, s = 0.f;
    for (int n = 0; n < chunk; ++n) {
        float v = base[n * 128 + f];
        m = fmaxf(m, v);
        s += v;
    }
    part[(size_t)b * 256 + f]       = m;
    part[(size_t)b * 256 + 128 + f] = s;
}

// ----------------------------------------------------------------------------
// MLP head with fused readout-finalize (bit-identical combine order).
__global__ __launch_bounds__(128) void mlp_kernel(const float* __restrict__ part1,
                                                  const float* __restrict__ part2,
                                                  const float* __restrict__ part3,
                                                  const float* __restrict__ L1w,
                                                  const float* __restrict__ L1b,
                                                  const float* __restrict__ L2w,
                                                  const float* __restrict__ L2b,
                                                  const float* __restrict__ L3w,
                                                  const float* __restrict__ L3b,
                                                  float* __restrict__ out) {
    __shared__ float z[256], z1[128], z2[64], z3[6];
    int g = blockIdx.x, t = threadIdx.x;
    float m1 = -INFINITY, s1 = 0.f, m2 = -INFINITY, s2 = 0.f, m3 = -INFINITY, s3 = 0.f;
    #pragma unroll
    for (int c = 0; c < 8; ++c) {
        size_t o = (size_t)(g * 8 + c) * 256;
        m1 = fmaxf(m1, part1[o + t]); s1 += part1[o + 128 + t];
        m2 = fmaxf(m2, part2[o + t]); s2 += part2[o + 128 + t];
        m3 = fmaxf(m3, part3[o + t]); s3 += part3[o + 128 + t];
    }
    z[t]       = fmaxf(m1, 0.f) + fmaxf(m2, 0.f) + fmaxf(m3, 0.f);
    z[t + 128] = fmaxf(s1 / 512.f, 0.f) + fmaxf(s2 / 256.f, 0.f) + fmaxf(s3 / 256.f, 0.f);
    __syncthreads();
    float a = L1b[t];
    for (int i = 0; i < 256; ++i) a += z[i] * L1w[i * 128 + t];
    z1[t] = fmaxf(a, 0.f);
    __syncthreads();
    if (t < 64) {
        float b = L2b[t];
        for (int i = 0; i < 128; ++i) b += z1[i] * L2w[i * 64 + t];
        z2[t] = fmaxf(b, 0.f);
    }
    __syncthreads();
    if (t < 6) {
        float c = L3b[t];
        for (int i = 0; i < 64; ++i) c += z2[i] * L3w[i * 6 + t];
        z3[t] = c;
    }
    __syncthreads();
    if (t == 0) {
        float m = z3[0];
        for (int i = 1; i < 6; ++i) m = fmaxf(m, z3[i]);
        float s = 0.f;
        for (int i = 0; i < 6; ++i) s += expf(z3[i] - m);
        float ls = m + logf(s);
        for (int i = 0; i < 6; ++i) out[g * 6 + i] = z3[i] - ls;
    }
}

// ----------------------------------------------------------------------------
extern "C" void kernel_launch(void* const* d_in, const int* in_sizes, int n_in,
                              void* d_out, int out_size, void* d_ws, size_t ws_size,
                              hipStream_t stream) {
    const float* x    = (const float*)d_in[0];
    const int*   ei   = (const int*)d_in[1];
    const float* W1   = (const float*)d_in[3];
    const float* b1   = (const float*)d_in[4];
    const float* ws1  = (const float*)d_in[5];
    const float* W2   = (const float*)d_in[6];
    const float* b2   = (const float*)d_in[7];
    const float* ws2  = (const float*)d_in[8];
    const float* W3   = (const float*)d_in[9];
    const float* b3   = (const float*)d_in[10];
    const float* ws3  = (const float*)d_in[11];
    const float* L1w  = (const float*)d_in[12];
    const float* L1b  = (const float*)d_in[13];
    const float* L2w  = (const float*)d_in[14];
    const float* L2b  = (const float*)d_in[15];
    const float* L3w  = (const float*)d_in[16];
    const float* L3b  = (const float*)d_in[17];
    float* out = (float*)d_out;

    // workspace layout (256B aligned regions)
    char* w = (char*)d_ws;
    auto alloc = [&](size_t nbytes) { char* p = w; w += (nbytes + 255) & ~(size_t)255; return p; };
    float* A     = (float*)alloc((size_t)NN1 * 128 * 4);   // h = X @ W
    float* Bf    = (float*)alloc((size_t)NN1 * 128 * 4);   // relu(out)
    float* P1    = (float*)alloc((size_t)NN1 * 64 * 4);    // partials P (16MB) -> later csrB
    float* P2    = (float*)alloc((size_t)NN3 * 128 * 4);   // dead buffer -> hosts bins
    int2*  csr2  = (int2*)alloc((size_t)(E_TOT + 64) * 8); // stage1 norm-fused csr / stage3 padded overlay
    int*   degA  = (int*)alloc((size_t)NN2 * 4);           // stage2 padded deg
    int*   degB  = (int*)alloc((size_t)NN3 * 4);           // stage3 padded deg
    int2*  off2A = (int2*)alloc((size_t)NN1 * 8);
    float* rs    = (float*)alloc((size_t)NN1 * 4);
    int*   perm  = (int*)alloc((size_t)NN1 * 4);           // stage1 degree-sorted node perm
    int*   np1   = (int*)alloc((size_t)NN1 * 4);
    int*   np2   = (int*)alloc((size_t)NN2 * 4);
    int*   sel   = (int*)alloc((size_t)NN2 * 4);
    float* scal  = (float*)alloc((size_t)NN2 * 4);
    float* score = (float*)alloc((size_t)NN1 * 4);
    float* part1 = (float*)alloc((size_t)NB * 8 * 256 * 4);
    float* part2 = (float*)alloc((size_t)NB * 8 * 256 * 4);
    float* part3 = (float*)alloc((size_t)NB * 8 * 256 * 4);
    int*   gcur  = (int*)alloc(64 * 4);
    int*   flag  = (int*)alloc(256);

    // overlays (regions dead at time of use)
    int*   bins = (int*)P2;    // stage-1 build scratch (P2 never written otherwise)
    float* Pp   = P1;          // stage-1 score partials (consumed by score1)
    int*   csrB = (int*)P1;    // stage-2 padded csr (written AFTER topk1): 8MB < 16MB
    int*   csrC = (int*)csr2;  // stage-3 padded csr: NN3*PSTR*4 = 4MB (csr2 dead then)

    probe_kernel<<<1, 64, 0, stream>>>(ei, flag, gcur, csr2);

    // ---------------- stage 1 (bin_pack and gemm1 un-merged: both DS-pipe-heavy,
    // merging serialized them at the shared CU LDS port) -------------------------
    bin_pack_kernel<<<E_TOT / 4096, 256, 0, stream>>>(ei, flag, bins, gcur);
    gemm_fused_kernel<<<NN1 / 128, 512, SMEM_PREP, stream>>>(x, nullptr, nullptr, W1,
                                                             A, nullptr, 64);
    graph_csr_kernel<<<NB, 1024, 0, stream>>>(bins, gcur, off2A, rs, csr2, perm);
    agg_lds_kernel<<<256, 1024, 0, stream>>>(A, csr2, off2A, rs, perm, b1, ws1, Bf, Pp);
    score1_kernel<<<NN1 / 256, 256, 0, stream>>>(Pp, score);
    topk_kernel<<<NB, 1024, 0, stream>>>(score, np1, sel, scal, 1024, 512);

    // ---------------- stage 2 (csr standalone; gemm with fused readout1) ---------
    csr_build_kernel<<<NN2 / 4, 256, 0, stream>>>(off2A, nullptr, (const int*)csr2, 2,
                                                  np1, sel, csrB, degA, rs, NN2);
    gemm_fused_kernel<<<NN2 / 128, 512, SMEM_PREP, stream>>>(Bf, sel, scal, W2, A,
                                                             part1, 64);
    agg_kernel<<<NN2 / 8, 256, 0, stream>>>(A, csrB, nullptr, degA, rs, b2, ws2,
                                            Bf, score, 512, 6, 1);
    topk_kernel<<<NB, 512, 0, stream>>>(score, np2, sel, scal, 512, 256);

    // ---------------- stage 3 (csr standalone; gemm with fused readout2) ---------
    csr_build_kernel<<<NN3 / 4, 256, 0, stream>>>(nullptr, degA, csrB, 1,
                                                  np2, sel, csrC, degB, rs, NN3);
    gemm_fused_kernel<<<NN3 / 128, 512, SMEM_PREP, stream>>>(Bf, sel, scal, W3, A,
                                                             part2, 32);
    agg_kernel<<<NN3 / 8, 256, 0, stream>>>(A, csrC, nullptr, degB, rs, b3, ws3,
                                            Bf, score, 256, 5, 1);
    readout_part_kernel<<<NB * 8, 128, 0, stream>>>(Bf, part3, 256);

    // ---------------- head (fused readout-finalize + MLP) ----------------
    mlp_kernel<<<NB, 128, 0, stream>>>(part1, part2, part3, L1w, L1b, L2w, L2b,
                                       L3w, L3b, out);
}

// Round 9
// 325.760 us; speedup vs baseline: 1.0357x; 1.0357x over previous
//
#include <hip/hip_runtime.h>
#include <math.h>

// Problem constants
#define E_TOT 1048576
#define NB    64          // graphs
#define HD    128         // hidden dim
#define NN1   65536       // nodes stage1 (64*1024)
#define NN2   32768       // nodes stage2 (64*512)
#define NN3   16384       // nodes stage3 (64*256)
#define CAP   18432       // per-graph edge bin capacity (mean 16384 + 16 sigma)
#define WST   140         // swizzled sW row stride (max pos 136 + 4)
#define PSTR  64          // padded CSR stride (ints/node); deg max ~45 (Poisson 16)
#define SMEM_PREP (2*16*128*4 + 2*16*WST*4)   // 34304B: gemm dbuf tiles

// ----------------------------------------------------------------------------
// edge_index dtype probe + gcur clear + csr2 tail pad clear (safe unguarded
// 8-wide edge-record loads in agg_lds_kernel).
__global__ void probe_kernel(const int* __restrict__ ei, int* __restrict__ flag,
                             int* __restrict__ gcur, int2* __restrict__ csr2) {
    int t = threadIdx.x;
    if (t < 64) { gcur[t] = 0; csr2[E_TOT + t] = make_int2(0, 0); }
    if (blockIdx.x == 0 && t == 0) {
        int w = 1;
        for (int i = 1; i < 64; i += 2) if (ei[i] != 0) { w = 0; break; }
        *flag = w;
    }
}

// ----------------------------------------------------------------------------
// Stage-1 edge build, phase 1 (device body): block-level counting sort by
// graph id. Runs inside a 512-thread block but the WORK is done by exactly
// threads 0..255 with the same per-thread items as the original 256-thread
// kernel (threads >=256 only transit the barriers) -> identical edge
// ordering behavior. smem overlay: hist[64] base[64] gpos[64] stage[4096].
__device__ __forceinline__ void bin_pack_body(char* smem, const int* __restrict__ ei,
                                              const int* __restrict__ wflag,
                                              int* __restrict__ bins,
                                              int* __restrict__ gcur, int bid) {
    int* hist  = (int*)smem;
    int* base  = hist + 64;
    int* gpos  = base + 64;
    int* stage = gpos + 64;
    const int t = threadIdx.x;
    const bool act = t < 256;
    const int wide = *wflag;
    const int e0 = bid * 4096;
    const int2* ei2 = (const int2*)ei;

    int pk[16];
    if (act) {
        #pragma unroll
        for (int j = 0; j < 16; ++j) {
            int e = e0 + j * 256 + t;
            int s, d;
            if (wide) { s = ei2[e].x; d = ei2[E_TOT + e].x; }
            else      { s = ei[e];    d = ei[E_TOT + e]; }
            int g = d >> 10;
            pk[j] = (g << 20) | ((d & 1023) << 10) | (s & 1023);
        }
    }
    if (t < 64) hist[t] = 0;
    __syncthreads();
    if (act) {
        #pragma unroll
        for (int j = 0; j < 16; ++j) atomicAdd(&hist[pk[j] >> 20], 1);
    }
    __syncthreads();
    if (t < 64) {
        int v = hist[t];
        int inc = v;
        #pragma unroll
        for (int d = 1; d < 64; d <<= 1) { int u = __shfl_up(inc, d); if (t >= d) inc += u; }
        base[t] = inc - v;                       // exclusive within tile
        gpos[t] = atomicAdd(&gcur[t], v);        // reserve global run
    }
    __syncthreads();
    if (t < 64) hist[t] = base[t];               // reuse as cursor
    __syncthreads();
    if (act) {
        #pragma unroll
        for (int j = 0; j < 16; ++j) {
            int p = atomicAdd(&hist[pk[j] >> 20], 1);
            stage[p] = pk[j];
        }
    }
    __syncthreads();
    if (act) {
        #pragma unroll
        for (int j = 0; j < 16; ++j) {
            int i = j * 256 + t;
            int v = stage[i];
            int g = v >> 20;
            int dst = gpos[g] + (i - base[g]);
            if (dst < CAP) bins[g * CAP + dst] = v;
        }
    }
}

// ----------------------------------------------------------------------------
// Tiled f32 GEMM body, 512 threads (dynamic-LDS): Y[bid*128..+128) = X' @ W,
// X' row r = sel ? X[sel[r]]*scal[r] : X[r]. 128x128 tile, BK=16 dbuf,
// swizzled sW; acc[4][8]/thread (8 waves/block). Bit-exact: each output
// element's k-accumulation order (k ascending, fmaf chain, staged x*sc
// multiply) is unchanged; only element->thread mapping moved.
// FUSED READOUT (part != nullptr): the staged sXT tile IS X' = h[sel]*scal.
// After each phase's sync, threads t < 2048/CH reduce feature (k0+kk) over
// chunk ch's CH rows serially in node order (bit-identical part values).
__device__ __forceinline__ void gemm_body(char* smem, const float* __restrict__ X,
                                          const int* __restrict__ sel,
                                          const float* __restrict__ scal,
                                          const float* __restrict__ W,
                                          float* __restrict__ Y, int bid,
                                          float* __restrict__ part, int CH) {
    float* sXT = (float*)smem;                 // [2][16][128] (k-major)
    float* sW  = sXT + 2 * 16 * 128;           // [2][16][WST]
    const int t = threadIdx.x;                 // 0..511
    const long long row0 = (long long)bid * 128;
    const int r0 = (t >> 4) << 2;              // 32 row groups x 4 rows
    const int c0 = (t & 15) << 3;              // 16 col groups x 8 cols
    const int wofs = c0 + ((c0 >> 5) << 2);
    const int lm  = t >> 2;                    // X-stage: row 0..127
    const int lk  = (t & 3) << 2;              // X-stage: k sub-offset 0/4/8/12
    const int wk  = t >> 5;                    // W-stage: k row 0..15
    const int wc4 = (t & 31) << 2;             // W-stage: col 0..124 (4-aligned)
    const int wpos = wc4 + ((wc4 >> 5) << 2);  // same col->pos map as reads

    const float* xrow;
    float sc;
    if (sel) { xrow = X + (long long)sel[row0 + lm] * 128; sc = scal[row0 + lm]; }
    else     { xrow = X + (row0 + lm) * 128;               sc = 1.f; }

    float acc[4][8];
    #pragma unroll
    for (int i = 0; i < 4; ++i)
        #pragma unroll
        for (int j = 0; j < 8; ++j) acc[i][j] = 0.f;

    {
        float4 xa = *(const float4*)(xrow + lk);
        float4 wa = *(const float4*)(W + wk * 128 + wc4);
        sXT[(lk + 0) * 128 + lm] = xa.x * sc; sXT[(lk + 1) * 128 + lm] = xa.y * sc;
        sXT[(lk + 2) * 128 + lm] = xa.z * sc; sXT[(lk + 3) * 128 + lm] = xa.w * sc;
        *(float4*)&sW[wk * WST + wpos] = wa;
    }
    int cur = 0;
    for (int k0 = 0; k0 < 128; k0 += 16) {
        __syncthreads();
        // fused readout: reduce current tile's 16 feature columns per chunk
        if (part) {
            int nu = 2048 / CH;                // 16 features x (128/CH) chunks
            if (t < nu) {
                int kk = t & 15, ch = t >> 4;
                const float* col = &sXT[(cur * 16 + kk) * 128 + ch * CH];
                float m = -INFINITY, s = 0.f;
                for (int n = 0; n < CH; ++n) {
                    float v = col[n];
                    m = fmaxf(m, v);
                    s += v;
                }
                size_t gc = (size_t)bid * (128 / CH) + ch;
                part[gc * 256 + k0 + kk]       = m;
                part[gc * 256 + 128 + k0 + kk] = s;
            }
        }
        const bool hasNext = (k0 + 16) < 128;
        float4 nxa, nwa;
        if (hasNext) {
            nxa = *(const float4*)(xrow + k0 + 16 + lk);
            nwa = *(const float4*)(W + (k0 + 16 + wk) * 128 + wc4);
        }
        #pragma unroll
        for (int kk = 0; kk < 16; ++kk) {
            float4 xa = *(const float4*)&sXT[(cur * 16 + kk) * 128 + r0];
            float4 wa = *(const float4*)&sW[(cur * 16 + kk) * WST + wofs];
            float4 wb = *(const float4*)&sW[(cur * 16 + kk) * WST + wofs + 4];
            float xr[4]  = {xa.x, xa.y, xa.z, xa.w};
            float wcv[8] = {wa.x, wa.y, wa.z, wa.w, wb.x, wb.y, wb.z, wb.w};
            #pragma unroll
            for (int i = 0; i < 4; ++i)
                #pragma unroll
                for (int j = 0; j < 8; ++j)
                    acc[i][j] = fmaf(xr[i], wcv[j], acc[i][j]);
        }
        if (hasNext) {
            int nxt = cur ^ 1;
            sXT[(nxt * 16 + lk + 0) * 128 + lm] = nxa.x * sc;
            sXT[(nxt * 16 + lk + 1) * 128 + lm] = nxa.y * sc;
            sXT[(nxt * 16 + lk + 2) * 128 + lm] = nxa.z * sc;
            sXT[(nxt * 16 + lk + 3) * 128 + lm] = nxa.w * sc;
            *(float4*)&sW[(nxt * 16 + wk) * WST + wpos] = nwa;
            cur = nxt;
        }
    }

    #pragma unroll
    for (int i = 0; i < 4; ++i) {
        float* yp = Y + (row0 + r0 + i) * 128 + c0;
        float4 o0; o0.x = acc[i][0]; o0.y = acc[i][1]; o0.z = acc[i][2]; o0.w = acc[i][3];
        float4 o1; o1.x = acc[i][4]; o1.y = acc[i][5]; o1.z = acc[i][6]; o1.w = acc[i][7];
        *(float4*)yp       = o0;
        *(float4*)(yp + 4) = o1;
    }
}

// ----------------------------------------------------------------------------
// Merged kernel: bin_pack (blocks [0,256)) + stage-1 GEMM (blocks [256,768)).
// (R8 showed un-merging regresses: overlap of mem-bound sort with VALU-bound
// GEMM beats separate serialized dispatches.)
__global__ __launch_bounds__(512) void prep1_kernel(const int* __restrict__ ei,
                                                    const int* __restrict__ wflag,
                                                    int* __restrict__ bins,
                                                    int* __restrict__ gcur,
                                                    const float* __restrict__ X,
                                                    const float* __restrict__ W1,
                                                    float* __restrict__ A) {
    extern __shared__ __align__(16) char smem[];
    if (blockIdx.x < 256) bin_pack_body(smem, ei, wflag, bins, gcur, blockIdx.x);
    else                  gemm_body(smem, X, nullptr, nullptr, W1, A, blockIdx.x - 256,
                                    nullptr, 64);
}

// ----------------------------------------------------------------------------
// Gather-GEMM + fused readout (stages 2/3).
__global__ __launch_bounds__(512) void gemm_fused_kernel(const float* __restrict__ Bf,
                                                         const int* __restrict__ sel,
                                                         const float* __restrict__ scal,
                                                         const float* __restrict__ W,
                                                         float* __restrict__ A,
                                                         float* __restrict__ part,
                                                         int CH) {
    extern __shared__ __align__(16) char smem[];
    gemm_body(smem, Bf, sel, scal, W, A, blockIdx.x, part, CH);
}

// ----------------------------------------------------------------------------
// Standalone pooled-CSR build -> PADDED layout (zero LDS -> full occupancy for
// the latency-bound map gathers). Survivor order = old order filtered ->
// bit-identical agg. old_stride 2 for int2 stage-1 csr.
__global__ __launch_bounds__(256) void csr_build_kernel(const int2* __restrict__ old_off2,
                                                        const int* __restrict__ old_deg,
                                                        const int* __restrict__ old_csr,
                                                        int old_stride,
                                                        const int* __restrict__ map,
                                                        const int* __restrict__ sel,
                                                        int* __restrict__ new_csr,
                                                        int* __restrict__ deg,
                                                        float* __restrict__ rs, int nnew) {
    int wid  = (blockIdx.x * blockDim.x + threadIdx.x) >> 6;
    int lane = threadIdx.x & 63;
    if (wid >= nnew) return;
    int old = sel[wid];
    int beg, end;
    if (old_off2) { int2 oe = old_off2[old]; beg = oe.x; end = oe.y; }
    else          { beg = old * PSTR; end = beg + old_deg[old]; }
    int out = wid * PSTR;
    int total = 0;
    for (int base = beg; base < end; base += 64) {
        int i = base + lane;
        int ns = -1;
        if (i < end) ns = map[old_csr[i * old_stride]];
        unsigned long long b = __ballot(ns >= 0);
        int pos = __popcll(b & ((1ULL << lane) - 1));
        if (ns >= 0 && total + pos < PSTR) new_csr[out + total + pos] = ns;
        total += __popcll(b);
    }
    if (total > PSTR) total = PSTR;
    if (lane == 0) {
        deg[wid] = total;
        rs[wid]  = rsqrtf((float)(total + 1));
    }
}

// ----------------------------------------------------------------------------
// Stage-1 edge build, phase 2: one block per graph -> int2 off2 + rs +
// norm-fused csr2 ({global src, rs[s]*rs[d]}) + degree-sorted perm (counting
// sort, ascending; used by agg_lds for divergence-free node grouping).
__global__ __launch_bounds__(1024) void graph_csr_kernel(const int* __restrict__ bins,
                                                         const int* __restrict__ gcur,
                                                         int2* __restrict__ off2,
                                                         float* __restrict__ rs,
                                                         int2* __restrict__ csr2,
                                                         int* __restrict__ perm) {
    __shared__ int   deg[1024];
    __shared__ int   cur[1024];
    __shared__ float rsl[1024];
    __shared__ int   wsum[16];
    __shared__ int   dh[64];
    __shared__ int   dc[64];
    __shared__ int   ebase_s;
    const int g = blockIdx.x, t = threadIdx.x;
    const int lane = t & 63, wv = t >> 6;

    if (t < 64) {
        int v = gcur[t];
        int inc = v;
        #pragma unroll
        for (int d = 1; d < 64; d <<= 1) { int u = __shfl_up(inc, d); if (t >= d) inc += u; }
        if (t == g) ebase_s = inc - v;
    }
    deg[t] = 0;
    if (t < 64) dh[t] = 0;
    __syncthreads();
    const int cnt = gcur[g];
    const int ebase = ebase_s;
    const int* bin = bins + g * CAP;

    for (int i = t; i < cnt; i += 1024)
        atomicAdd(&deg[(bin[i] >> 10) & 1023], 1);
    __syncthreads();

    int dv = deg[t];
    int dcap = dv < 63 ? dv : 63;
    atomicAdd(&dh[dcap], 1);                     // degree histogram
    int inc = dv;
    #pragma unroll
    for (int d = 1; d < 64; d <<= 1) { int u = __shfl_up(inc, d); if (lane >= d) inc += u; }
    if (lane == 63) wsum[wv] = inc;
    __syncthreads();
    if (t < 16) {
        int v = wsum[t];
        int inc2 = v;
        #pragma unroll
        for (int d = 1; d < 16; d <<= 1) { int u = __shfl_up(inc2, d); if (t >= d) inc2 += u; }
        wsum[t] = inc2 - v;
    }
    if (t >= 64 && t < 128) {                    // wave 1: degree-hist prefix sum
        int l2 = t - 64;
        int v2 = dh[l2];
        int inc3 = v2;
        #pragma unroll
        for (int d = 1; d < 64; d <<= 1) { int u = __shfl_up(inc3, d); if (l2 >= d) inc3 += u; }
        dc[l2] = inc3 - v2;                      // exclusive base cursor
    }
    __syncthreads();
    int ex = inc - dv + wsum[wv];
    int beg = ebase + ex;
    off2[g * 1024 + t] = make_int2(beg, beg + dv);
    float rv = rsqrtf((float)(dv + 1));
    rs[g * 1024 + t] = rv;
    rsl[t] = rv;
    cur[t] = ex;
    int r2 = atomicAdd(&dc[dcap], 1);            // rank in ascending-degree order
    perm[g * 1024 + r2] = t;
    __syncthreads();

    for (int i = t; i < cnt; i += 1024) {
        int v = bin[i];
        int s = v & 1023;
        int d = (v >> 10) & 1023;
        int p = atomicAdd(&cur[d], 1);
        csr2[ebase + p] = make_int2((g << 10) + s, __float_as_int(rsl[s] * rsl[d]));
    }
}

// ----------------------------------------------------------------------------
// Stage-1 GCN aggregation, LDS-staged per (graph, 32-feature chunk).
// grid = fc*64 + g; block = 1024 thr; LDS = 1024 x 36 floats (144KB).
// Degree-sorted node assignment (perm); direct same-address edge loads
// (VMEM broadcast). Bit-exact order throughout.
__global__ __launch_bounds__(1024) void agg_lds_kernel(const float* __restrict__ h,
                                                       const int2* __restrict__ csr2,
                                                       const int2* __restrict__ off2,
                                                       const float* __restrict__ rs,
                                                       const int* __restrict__ perm,
                                                       const float* __restrict__ bias,
                                                       const float* __restrict__ ws,
                                                       float* __restrict__ hrelu,
                                                       float* __restrict__ P) {
    __shared__ float sh[1024 * 36];
    const int t  = threadIdx.x;
    const int g  = blockIdx.x & 63;
    const int fc = blockIdx.x >> 6;
    const int nbase = g << 10;
    const float* hg = h + (size_t)nbase * 128 + fc * 32;

    // stage: 1024 rows x 32 floats; 8 consecutive lanes read 128B of one row
    #pragma unroll
    for (int it = 0; it < 8; ++it) {
        int i = it * 1024 + t;
        int r = i >> 3, p = i & 7;
        float4 v4 = *(const float4*)(hg + (size_t)r * 128 + p * 4);
        *(float4*)&sh[r * 36 + p * 4] = v4;
    }
    __syncthreads();

    const int q   = t & 7;         // feature sub-chunk lane (features qb..qb+3)
    const int grp = t >> 3;        // node group 0..127 (8 lanes each)
    const int qb  = q << 2;

    float4 bb = *(const float4*)(bias + fc * 32 + qb);
    float4 ww = *(const float4*)(ws   + fc * 32 + qb);

    for (int pass = 0; pass < 8; ++pass) {
        int lv = perm[nbase + pass * 128 + grp];   // sorted rank -> actual node
        int v  = nbase + lv;
        int2 oe = off2[v];
        int beg = oe.x, end = oe.y;
        float rv = rs[v];
        float a0 = 0.f, a1 = 0.f, a2 = 0.f, a3 = 0.f;

        int eb = beg;
        for (; eb + 8 <= end; eb += 8) {           // full batches, no guard
            #pragma unroll
            for (int j = 0; j < 8; ++j) {
                int2 e = csr2[eb + j];             // same addr across group -> bcast
                float nj = __int_as_float(e.y);
                const float4 hv4 = *(const float4*)&sh[(e.x & 1023) * 36 + qb];
                a0 = fmaf(hv4.x, nj, a0); a1 = fmaf(hv4.y, nj, a1);
                a2 = fmaf(hv4.z, nj, a2); a3 = fmaf(hv4.w, nj, a3);
            }
        }
        if (eb < end) {                            // tail batch, norm=0 padding
            #pragma unroll
            for (int j = 0; j < 8; ++j) {
                int2 e = csr2[eb + j];             // pad-safe (64-entry zero tail)
                float nj = (eb + j < end) ? __int_as_float(e.y) : 0.f;
                const float4 hv4 = *(const float4*)&sh[(e.x & 1023) * 36 + qb];
                a0 = fmaf(hv4.x, nj, a0); a1 = fmaf(hv4.y, nj, a1);
                a2 = fmaf(hv4.z, nj, a2); a3 = fmaf(hv4.w, nj, a3);
            }
        }

        float4 hv = *(const float4*)&sh[lv * 36 + qb];
        float inv = rv * rv;
        float o0 = a0 + hv.x * inv + bb.x;
        float o1 = a1 + hv.y * inv + bb.y;
        float o2 = a2 + hv.z * inv + bb.z;
        float o3 = a3 + hv.w * inv + bb.w;

        // butterfly leaf partials for lane li = fc*8+q (exact old values)
        float pa = o0 * ww.x + o1 * ww.y;
        float pb = o2 * ww.z + o3 * ww.w;
        *(float2*)(P + (size_t)v * 64 + (fc * 8 + q) * 2) = make_float2(pa, pb);

        float4 o;
        o.x = fmaxf(o0, 0.f); o.y = fmaxf(o1, 0.f);
        o.z = fmaxf(o2, 0.f); o.w = fmaxf(o3, 0.f);
        *(float4*)(hrelu + (size_t)v * 128 + fc * 32 + qb) = o;
    }
}

// ----------------------------------------------------------------------------
// GCN aggregation, dual-node waves (stages 2/3, padded CSR + rs gather).
__global__ __launch_bounds__(256) void agg_kernel(const float* __restrict__ h,
                                                  const int* __restrict__ csr,
                                                  const int2* __restrict__ off2,
                                                  const int* __restrict__ degp,
                                                  const float* __restrict__ rs,
                                                  const float* __restrict__ bias,
                                                  const float* __restrict__ ws,
                                                  float* __restrict__ hrelu,
                                                  float* __restrict__ score,
                                                  int npg, int lbshift, int padded) {
    const int lane = threadIdx.x & 63;
    const int wvb  = threadIdx.x >> 6;      // wave in block: 0..3
    const int half = lane >> 5;             // 0/1: which node of the wave
    const int li   = lane & 31;
    int b   = blockIdx.x;
    int xcd = b & 7;
    int i   = b >> 3;
    int gi  = i >> lbshift;
    int lb  = i & ((1 << lbshift) - 1);
    int g   = xcd + (gi << 3);
    int v   = g * npg + (lb << 3) + (wvb << 1) + half;   // 8 nodes/block, 2/wave

    int beg, end;
    if (padded) { beg = v * PSTR; end = beg + degp[v]; }
    else        { int2 oe = off2[v]; beg = oe.x; end = oe.y; }
    float rv = rs[v];
    const float4* h4 = (const float4*)h;
    float ax = 0.f, ay = 0.f, az = 0.f, aw = 0.f;

    for (int base = beg; base < end; base += 32) {
        int idx = base + li;
        int sv = (idx < end) ? csr[idx] : 0;
        int m = end - base; if (m > 32) m = 32;
        int j = 0;
        for (; j + 8 <= m; j += 8) {
            int s0 = __shfl(sv, j,     32);
            int s1 = __shfl(sv, j + 1, 32);
            int s2 = __shfl(sv, j + 2, 32);
            int s3 = __shfl(sv, j + 3, 32);
            int s4 = __shfl(sv, j + 4, 32);
            int s5 = __shfl(sv, j + 5, 32);
            int s6 = __shfl(sv, j + 6, 32);
            int s7 = __shfl(sv, j + 7, 32);
            float n0 = rs[s0] * rv, n1 = rs[s1] * rv, n2 = rs[s2] * rv, n3 = rs[s3] * rv;
            float n4 = rs[s4] * rv, n5 = rs[s5] * rv, n6 = rs[s6] * rv, n7 = rs[s7] * rv;
            float4 v0 = h4[(long long)s0 * 32 + li];
            float4 v1 = h4[(long long)s1 * 32 + li];
            float4 v2 = h4[(long long)s2 * 32 + li];
            float4 v3 = h4[(long long)s3 * 32 + li];
            float4 v4 = h4[(long long)s4 * 32 + li];
            float4 v5 = h4[(long long)s5 * 32 + li];
            float4 v6 = h4[(long long)s6 * 32 + li];
            float4 v7 = h4[(long long)s7 * 32 + li];
            ax = fmaf(v0.x, n0, ax); ay = fmaf(v0.y, n0, ay); az = fmaf(v0.z, n0, az); aw = fmaf(v0.w, n0, aw);
            ax = fmaf(v1.x, n1, ax); ay = fmaf(v1.y, n1, ay); az = fmaf(v1.z, n1, az); aw = fmaf(v1.w, n1, aw);
            ax = fmaf(v2.x, n2, ax); ay = fmaf(v2.y, n2, ay); az = fmaf(v2.z, n2, az); aw = fmaf(v2.w, n2, aw);
            ax = fmaf(v3.x, n3, ax); ay = fmaf(v3.y, n3, ay); az = fmaf(v3.z, n3, az); aw = fmaf(v3.w, n3, aw);
            ax = fmaf(v4.x, n4, ax); ay = fmaf(v4.y, n4, ay); az = fmaf(v4.z, n4, az); aw = fmaf(v4.w, n4, aw);
            ax = fmaf(v5.x, n5, ax); ay = fmaf(v5.y, n5, ay); az = fmaf(v5.z, n5, az); aw = fmaf(v5.w, n5, aw);
            ax = fmaf(v6.x, n6, ax); ay = fmaf(v6.y, n6, ay); az = fmaf(v6.z, n6, az); aw = fmaf(v6.w, n6, aw);
            ax = fmaf(v7.x, n7, ax); ay = fmaf(v7.y, n7, ay); az = fmaf(v7.z, n7, az); aw = fmaf(v7.w, n7, aw);
        }
        for (; j < m; ++j) {
            int s = __shfl(sv, j, 32);
            float n = rs[s] * rv;
            float4 vv = h4[(long long)s * 32 + li];
            ax = fmaf(vv.x, n, ax); ay = fmaf(vv.y, n, ay);
            az = fmaf(vv.z, n, az); aw = fmaf(vv.w, n, aw);
        }
    }

    float4 hv = h4[(long long)v * 32 + li];
    float inv = rv * rv;
    float4 bb = ((const float4*)bias)[li];
    float4 ww = ((const float4*)ws)[li];
    float o0 = ax + hv.x * inv + bb.x;
    float o1 = ay + hv.y * inv + bb.y;
    float o2 = az + hv.z * inv + bb.z;
    float o3 = aw + hv.w * inv + bb.w;

    // bit-exact emulation of the old 64-lane score butterfly
    float pa = o0 * ww.x + o1 * ww.y;   // old lane 2*li partial
    float pb = o2 * ww.z + o3 * ww.w;   // old lane 2*li+1 partial
    #pragma unroll
    for (int dd = 16; dd; dd >>= 1) {
        pa += __shfl_xor(pa, dd, 32);
        pb += __shfl_xor(pb, dd, 32);
    }
    float p = pa + pb;                  // old d=1 step, lane-0 (even) order
    if (li == 0) score[v] = p;

    float4 o;
    o.x = fmaxf(o0, 0.f); o.y = fmaxf(o1, 0.f);
    o.z = fmaxf(o2, 0.f); o.w = fmaxf(o3, 0.f);
    ((float4*)hrelu)[(long long)v * 32 + li] = o;
}

// ----------------------------------------------------------------------------
// per-graph top-k via bitonic sort (descending). Launch with n threads (n<=1024).
// P != null: compute score from per-lane butterfly partials (exact 31-add tree
// per array, same operand order as the old __shfl_xor butterfly at lane 0 —
// this P-path passed absmax=0 in a prior round).
__global__ __launch_bounds__(1024) void topk_kernel(const float* __restrict__ score,
                                                    const float* __restrict__ P,
                                                    int* __restrict__ newpos,
                                                    int* __restrict__ sel,
                                                    float* __restrict__ scale,
                                                    int n, int k) {
    __shared__ float key[1024];
    __shared__ int   kid[1024];
    int g = blockIdx.x, t = threadIdx.x;
    float sc;
    if (P) {
        const float* buf = P + (size_t)(g * n + t) * 64;
        float a[32], b[32];
        #pragma unroll
        for (int i2 = 0; i2 < 16; ++i2) {
            float4 v4 = *(const float4*)(buf + i2 * 4);
            a[i2 * 2]     = v4.x; b[i2 * 2]     = v4.y;
            a[i2 * 2 + 1] = v4.z; b[i2 * 2 + 1] = v4.w;
        }
        float ua[16], ub[16];
        #pragma unroll
        for (int l = 0; l < 16; ++l) { ua[l] = a[l] + a[l + 16]; ub[l] = b[l] + b[l + 16]; }
        float va[8], vb[8];
        #pragma unroll
        for (int l = 0; l < 8; ++l) { va[l] = ua[l] + ua[l + 8]; vb[l] = ub[l] + ub[l + 8]; }
        float wa[4], wb[4];
        #pragma unroll
        for (int l = 0; l < 4; ++l) { wa[l] = va[l] + va[l + 4]; wb[l] = vb[l] + vb[l + 4]; }
        float xa0 = wa[0] + wa[2], xa1 = wa[1] + wa[3];
        float xb0 = wb[0] + wb[2], xb1 = wb[1] + wb[3];
        sc = (xa0 + xa1) + (xb0 + xb1);
    } else {
        sc = score[g * n + t];
    }
    key[t] = sc;
    kid[t] = t;
    __syncthreads();
    for (int kk = 2; kk <= n; kk <<= 1) {
        for (int j = kk >> 1; j > 0; j >>= 1) {
            int ixj = t ^ j;
            if (ixj > t) {
                bool dir = ((t & kk) == 0);
                float a = key[t], b = key[ixj];
                if ((a < b) == dir) {
                    key[t] = b; key[ixj] = a;
                    int tmp = kid[t]; kid[t] = kid[ixj]; kid[ixj] = tmp;
                }
            }
            __syncthreads();
        }
    }
    int old = g * n + kid[t];
    if (t < k) {
        int nid = g * k + t;
        newpos[old] = nid;
        sel[nid]    = old;
        scale[nid]  = tanhf(key[t]);
    } else {
        newpos[old] = -1;
    }
}

// ----------------------------------------------------------------------------
// MLP head with fused stage-3 readout + readout-finalize (bit-identical
// combine order: part3 chunk c = serial max/sum over rows c*32..c*32+31 in
// node order, combined c-ascending — exactly the old readout_part + mlp).
__global__ __launch_bounds__(128) void mlp_kernel(const float* __restrict__ part1,
                                                  const float* __restrict__ part2,
                                                  const float* __restrict__ Bf,
                                                  const float* __restrict__ L1w,
                                                  const float* __restrict__ L1b,
                                                  const float* __restrict__ L2w,
                                                  const float* __restrict__ L2b,
                                                  const float* __restrict__ L3w,
                                                  const float* __restrict__ L3b,
                                                  float* __restrict__ out) {
    __shared__ float z[256], z1[128], z2[64], z3[6];
    int g = blockIdx.x, t = threadIdx.x;
    float m1 = -INFINITY, s1 = 0.f, m2 = -INFINITY, s2 = 0.f, m3 = -INFINITY, s3 = 0.f;
    #pragma unroll
    for (int c = 0; c < 8; ++c) {
        size_t o = (size_t)(g * 8 + c) * 256;
        m1 = fmaxf(m1, part1[o + t]); s1 += part1[o + 128 + t];
        m2 = fmaxf(m2, part2[o + t]); s2 += part2[o + 128 + t];
        // stage-3 readout chunk c, inline (identical loop to readout_part)
        const float* base = Bf + ((size_t)g * 256 + c * 32) * 128;
        float mc = -INFINITY, sc = 0.f;
        for (int n = 0; n < 32; ++n) {
            float v = base[n * 128 + t];
            mc = fmaxf(mc, v);
            sc += v;
        }
        m3 = fmaxf(m3, mc); s3 += sc;
    }
    z[t]       = fmaxf(m1, 0.f) + fmaxf(m2, 0.f) + fmaxf(m3, 0.f);
    z[t + 128] = fmaxf(s1 / 512.f, 0.f) + fmaxf(s2 / 256.f, 0.f) + fmaxf(s3 / 256.f, 0.f);
    __syncthreads();
    float a = L1b[t];
    for (int i = 0; i < 256; ++i) a += z[i] * L1w[i * 128 + t];
    z1[t] = fmaxf(a, 0.f);
    __syncthreads();
    if (t < 64) {
        float b = L2b[t];
        for (int i = 0; i < 128; ++i) b += z1[i] * L2w[i * 64 + t];
        z2[t] = fmaxf(b, 0.f);
    }
    __syncthreads();
    if (t < 6) {
        float c = L3b[t];
        for (int i = 0; i < 64; ++i) c += z2[i] * L3w[i * 6 + t];
        z3[t] = c;
    }
    __syncthreads();
    if (t == 0) {
        float m = z3[0];
        for (int i = 1; i < 6; ++i) m = fmaxf(m, z3[i]);
        float s = 0.f;
        for (int i = 0; i < 6; ++i) s += expf(z3[i] - m);
        float ls = m + logf(s);
        for (int i = 0; i < 6; ++i) out[g * 6 + i] = z3[i] - ls;
    }
}

// ----------------------------------------------------------------------------
extern "C" void kernel_launch(void* const* d_in, const int* in_sizes, int n_in,
                              void* d_out, int out_size, void* d_ws, size_t ws_size,
                              hipStream_t stream) {
    const float* x    = (const float*)d_in[0];
    const int*   ei   = (const int*)d_in[1];
    const float* W1   = (const float*)d_in[3];
    const float* b1   = (const float*)d_in[4];
    const float* ws1  = (const float*)d_in[5];
    const float* W2   = (const float*)d_in[6];
    const float* b2   = (const float*)d_in[7];
    const float* ws2  = (const float*)d_in[8];
    const float* W3   = (const float*)d_in[9];
    const float* b3   = (const float*)d_in[10];
    const float* ws3  = (const float*)d_in[11];
    const float* L1w  = (const float*)d_in[12];
    const float* L1b  = (const float*)d_in[13];
    const float* L2w  = (const float*)d_in[14];
    const float* L2b  = (const float*)d_in[15];
    const float* L3w  = (const float*)d_in[16];
    const float* L3b  = (const float*)d_in[17];
    float* out = (float*)d_out;

    // workspace layout (256B aligned regions)
    char* w = (char*)d_ws;
    auto alloc = [&](size_t nbytes) { char* p = w; w += (nbytes + 255) & ~(size_t)255; return p; };
    float* A     = (float*)alloc((size_t)NN1 * 128 * 4);   // h = X @ W
    float* Bf    = (float*)alloc((size_t)NN1 * 128 * 4);   // relu(out)
    float* P1    = (float*)alloc((size_t)NN1 * 64 * 4);    // partials P (16MB) -> later csrB
    float* P2    = (float*)alloc((size_t)NN3 * 128 * 4);   // dead buffer -> hosts bins
    int2*  csr2  = (int2*)alloc((size_t)(E_TOT + 64) * 8); // stage1 norm-fused csr / stage3 padded overlay
    int*   degA  = (int*)alloc((size_t)NN2 * 4);           // stage2 padded deg
    int*   degB  = (int*)alloc((size_t)NN3 * 4);           // stage3 padded deg
    int2*  off2A = (int2*)alloc((size_t)NN1 * 8);
    float* rs    = (float*)alloc((size_t)NN1 * 4);
    int*   perm  = (int*)alloc((size_t)NN1 * 4);           // stage1 degree-sorted node perm
    int*   np1   = (int*)alloc((size_t)NN1 * 4);
    int*   np2   = (int*)alloc((size_t)NN2 * 4);
    int*   sel   = (int*)alloc((size_t)NN2 * 4);
    float* scal  = (float*)alloc((size_t)NN2 * 4);
    float* score = (float*)alloc((size_t)NN1 * 4);
    float* part1 = (float*)alloc((size_t)NB * 8 * 256 * 4);
    float* part2 = (float*)alloc((size_t)NB * 8 * 256 * 4);
    int*   gcur  = (int*)alloc(64 * 4);
    int*   flag  = (int*)alloc(256);

    // overlays (regions dead at time of use)
    int*   bins = (int*)P2;    // stage-1 build scratch (P2 never written otherwise)
    float* Pp   = P1;          // stage-1 score partials (consumed by topk1)
    int*   csrB = (int*)P1;    // stage-2 padded csr (written AFTER topk1): 8MB < 16MB
    int*   csrC = (int*)csr2;  // stage-3 padded csr: NN3*PSTR*4 = 4MB (csr2 dead then)

    probe_kernel<<<1, 64, 0, stream>>>(ei, flag, gcur, csr2);

    // ---------------- stage 1 ----------------------------------------------------
    prep1_kernel<<<768, 512, SMEM_PREP, stream>>>(ei, flag, bins, gcur, x, W1, A);
    graph_csr_kernel<<<NB, 1024, 0, stream>>>(bins, gcur, off2A, rs, csr2, perm);
    agg_lds_kernel<<<256, 1024, 0, stream>>>(A, csr2, off2A, rs, perm, b1, ws1, Bf, Pp);
    topk_kernel<<<NB, 1024, 0, stream>>>(nullptr, Pp, np1, sel, scal, 1024, 512);

    // ---------------- stage 2 (csr standalone; gemm with fused readout1) ---------
    csr_build_kernel<<<NN2 / 4, 256, 0, stream>>>(off2A, nullptr, (const int*)csr2, 2,
                                                  np1, sel, csrB, degA, rs, NN2);
    gemm_fused_kernel<<<NN2 / 128, 512, SMEM_PREP, stream>>>(Bf, sel, scal, W2, A,
                                                             part1, 64);
    agg_kernel<<<NN2 / 8, 256, 0, stream>>>(A, csrB, nullptr, degA, rs, b2, ws2,
                                            Bf, score, 512, 6, 1);
    topk_kernel<<<NB, 512, 0, stream>>>(score, nullptr, np2, sel, scal, 512, 256);

    // ---------------- stage 3 (csr standalone; gemm with fused readout2) ---------
    csr_build_kernel<<<NN3 / 4, 256, 0, stream>>>(nullptr, degA, csrB, 1,
                                                  np2, sel, csrC, degB, rs, NN3);
    gemm_fused_kernel<<<NN3 / 128, 512, SMEM_PREP, stream>>>(Bf, sel, scal, W3, A,
                                                             part2, 32);
    agg_kernel<<<NN3 / 8, 256, 0, stream>>>(A, csrC, nullptr, degB, rs, b3, ws3,
                                            Bf, score, 256, 5, 1);

    // ---------------- head (fused stage-3 readout + MLP) ----------------
    mlp_kernel<<<NB, 128, 0, stream>>>(part1, part2, Bf, L1w, L1b, L2w, L2b,
                                       L3w, L3b, out);
}